// Round 6
// baseline (133.383 us; speedup 1.0000x reference)
//
#include <hip/hip_runtime.h>
#include <hip/hip_fp16.h>

// out[ns,d] = sum_{l=0..7} w[l, x[ns,l], d];  NS=16384, L=8, K=1024, D=1024
//
// Phase 1: transpose+convert w fp32 [l][k][d] -> wt fp16 [l][d4][k] (h4 = 4
//          fp16 = one 4-float d-slice entry, 8 B). 16 MiB in d_ws.
// Phase 2: gather with LDS-resident weights. Block owns slice s (4 floats of
//          d) and one ns-half; stages wt[.][s][.] = 64 KiB into LDS; all
//          gathers are ds_read_b64 (bypasses the L1-miss-queue x L2-latency
//          wall that capped the L2-gather design at ~28 us).
//          Stores are 16 B/lane quarter-lines; sibling slices {4j..4j+3}
//          share g&7 -> same XCD -> partial lines merge in that XCD's L2.

#define NSALL  16384
#define LVL    8
#define KK     1024
#define DD     1024
#define NSLICE 256          // 4-float d-slices
#define GT     512          // gather threads/block

typedef _Float16 h4  __attribute__((ext_vector_type(4)));
typedef float    f4  __attribute__((ext_vector_type(4)));

// ---------- Phase 1: w[l][k][d] fp32 -> wt[(l*256+d4)*1024 + k] fp16x4 ----
// 512 blocks x 256 thr. Block = (l, k0-chunk of 64, d4-quarter).
// lane = k (64 consecutive) -> reads stride 4 KiB (L1 reuses each 64 B line
// over 4 sequential d4 iters); writes 64 lanes x 8 B = 512 B contiguous.
__global__ __launch_bounds__(256) void transpose_convert(
    const float* __restrict__ w, h4* __restrict__ wt)
{
    const int l  = blockIdx.x >> 6;                 // 0..7
    const int k0 = ((blockIdx.x >> 2) & 15) << 6;   // 0,64,..,960
    const int q  = blockIdx.x & 3;                  // d4 quarter
    const int wv = threadIdx.x >> 6;                // wave 0..3
    const int k  = k0 + (threadIdx.x & 63);

    const float* src = w + ((size_t)(l * KK + k) * DD);
    const int d4base = q * 64 + wv * 16;
#pragma unroll 4
    for (int i = 0; i < 16; ++i) {
        const int d4 = d4base + i;
        const f4 v = *reinterpret_cast<const f4*>(src + d4 * 4);
        wt[((size_t)(l * NSLICE + d4) << 10) + k] = __builtin_convertvector(v, h4);
    }
}

// ---------- Phase 2: LDS-resident gather ----------------------------------
// 512 blocks = 256 slices x 2 ns-halves; 512 threads; 64 KiB static LDS
// (2 blocks/CU co-resident: 128 KiB <= 160 KiB).
// Block-id encoding: sibling slices 4j..4j+3 (same 64 B out-line) share
// g&7 -> same XCD under round-robin dispatch -> L2 merges partial lines.
__global__ __launch_bounds__(GT) void gather_kernel(
    const int* __restrict__ x, const h4* __restrict__ wt,
    float* __restrict__ out)
{
    const int g     = blockIdx.x;
    const int low3  = g & 7;
    const int inner = g >> 3;
    const int jhi   = inner >> 3;        // 0..7
    const int rh    = inner & 7;
    const int r     = rh >> 1;           // 0..3
    const int half  = rh & 1;            // ns half
    const int j     = jhi * 8 + low3;    // 0..63
    const int s     = j * 4 + r;         // slice 0..255

    __shared__ h4 lw[LVL * KK];          // 64 KiB
    const int t = threadIdx.x;

    // Stage slice s: per level, 1024 h4 entries = 8 KiB contiguous.
#pragma unroll
    for (int l = 0; l < LVL; ++l) {
        const h4* src = wt + ((size_t)(l * NSLICE + s) << 10) + t * 2;
        *reinterpret_cast<int4*>(&lw[l * KK + t * 2]) =
            *reinterpret_cast<const int4*>(src);
    }
    __syncthreads();

    const int4* x4 = reinterpret_cast<const int4*>(x);
    const int ns_base = half * (NSALL / 2);

    // Software-pipelined index prefetch; lanes -> consecutive ns.
    int ns = ns_base + t;
    int4 a0 = x4[(size_t)ns * 2];
    int4 a1 = x4[(size_t)ns * 2 + 1];
#pragma unroll
    for (int tile = 0; tile < (NSALL / 2) / GT; ++tile) {
        const int ns_cur = ns;
        const int4 c0 = a0, c1 = a1;
        if (tile < (NSALL / 2) / GT - 1) {
            ns = ns_base + (tile + 1) * GT + t;
            a0 = x4[(size_t)ns * 2];
            a1 = x4[(size_t)ns * 2 + 1];
        }
        h4 p0 = lw[         c0.x] + lw[    KK + c0.y];
        h4 p1 = lw[2 * KK + c0.z] + lw[3 * KK + c0.w];
        h4 p2 = lw[4 * KK + c1.x] + lw[5 * KK + c1.y];
        h4 p3 = lw[6 * KK + c1.z] + lw[7 * KK + c1.w];
        const h4 acc = (p0 + p1) + (p2 + p3);
        const f4 f = __builtin_convertvector(acc, f4);
        // plain (mergeable) store: 16 B at out[ns_cur, s*4]
        *reinterpret_cast<f4*>(out + (size_t)ns_cur * DD + s * 4) = f;
    }
}

extern "C" void kernel_launch(void* const* d_in, const int* in_sizes, int n_in,
                              void* d_out, int out_size, void* d_ws, size_t ws_size,
                              hipStream_t stream) {
    const int*   x = (const int*)d_in[0];
    const float* w = (const float*)d_in[1];
    float*     out = (float*)d_out;
    h4*         wt = (h4*)d_ws;          // 16 MiB fp16 transposed weights

    transpose_convert<<<dim3(512), dim3(256), 0, stream>>>(w, wt);
    gather_kernel<<<dim3(512), dim3(GT), 0, stream>>>(x, wt, out);
}

// Round 7
// 130.584 us; speedup vs baseline: 1.0214x; 1.0214x over previous
//
#include <hip/hip_runtime.h>
#include <hip/hip_fp16.h>

// out[ns,d] = sum_{l=0..7} w[l, x[ns,l], d];  NS=16384, L=8, K=1024, D=1024
//
// Proven structure (round 5): fp32->fp16 convert pass, then XCD-partitioned
// L2 gather (chunk = blockIdx&7 -> each XCD touches only its 2 MiB fp16
// weight slice; FETCH 235->34 MB validated in round 3).
// Round-7 deltas: nontemporal gather loads (no L1 allocation; zero reuse),
// 64 rows/block x 2 passes (2048 blocks, amortized index staging),
// 16-float/thread nt-read convert.

#define NS      16384
#define LVL     8
#define KK      1024
#define DD      1024
#define NCH     8                 // d-chunks (== XCD count)
#define DCH     (DD / NCH)        // 128 elements per chunk
#define THREADS 256

typedef _Float16 h8   __attribute__((ext_vector_type(8)));
typedef float    f32x4 __attribute__((ext_vector_type(4)));
typedef float    f32x8 __attribute__((ext_vector_type(8)));

// ---- convert: w fp32 -> wh fp16, same layout. 16 floats/thread. ----------
__global__ __launch_bounds__(THREADS) void convert_w_kernel(
    const float* __restrict__ w, _Float16* __restrict__ wh)
{
    const size_t i = ((size_t)blockIdx.x * THREADS + threadIdx.x) * 16;
    const f32x8 v0 = __builtin_nontemporal_load(
        reinterpret_cast<const f32x8*>(w + i));
    const f32x8 v1 = __builtin_nontemporal_load(
        reinterpret_cast<const f32x8*>(w + i + 8));
    *reinterpret_cast<h8*>(wh + i)     = __builtin_convertvector(v0, h8);
    *reinterpret_cast<h8*>(wh + i + 8) = __builtin_convertvector(v1, h8);
}

// ---- gather: 2048 blocks = 256 row-groups(64 rows) x 8 chunks ------------
__global__ __launch_bounds__(THREADS, 4) void multi_embedding_kernel(
    const int* __restrict__ x,          // (NS, L) int32
    const _Float16* __restrict__ wh,    // (L, K, D) fp16 (in d_ws)
    float* __restrict__ out)            // (NS, D) fp32
{
    const int chunk = blockIdx.x & (NCH - 1);      // -> XCD id (round-robin)
    const int grp   = blockIdx.x >> 3;             // 0..255
    const int tid   = threadIdx.x;
    const int ns0   = grp * 64;

    // Stage 64 rows x 8 indices = 512 ints (2 KiB): one int2 per thread.
    __shared__ int sidx[64 * LVL];
    reinterpret_cast<int2*>(sidx)[tid] =
        reinterpret_cast<const int2*>(x)[(size_t)ns0 * 4 + tid];
    __syncthreads();
    const int4* s4 = reinterpret_cast<const int4*>(sidx);

    const int lane = tid & 15;       // 8 fp16 (16 B) per lane within chunk
    const int rg   = tid >> 4;       // 0..15
    const _Float16* wl = wh + (size_t)chunk * DCH + (size_t)lane * 8;

#pragma unroll
    for (int p = 0; p < 2; ++p) {
        const int rowA = rg + 32 * p;
        const int rowB = rowA + 16;

        const int4 a0 = s4[rowA * 2], a1 = s4[rowA * 2 + 1];
        const int4 b0 = s4[rowB * 2], b1 = s4[rowB * 2 + 1];
        const int idxA[LVL] = { a0.x, a0.y, a0.z, a0.w, a1.x, a1.y, a1.z, a1.w };
        const int idxB[LVL] = { b0.x, b0.y, b0.z, b0.w, b1.x, b1.y, b1.z, b1.w };

        h8 accA = __builtin_nontemporal_load(reinterpret_cast<const h8*>(
            wl + ((size_t)idxA[0] << 10)));
        h8 accB = __builtin_nontemporal_load(reinterpret_cast<const h8*>(
            wl + ((size_t)idxB[0] << 10)));
#pragma unroll
        for (int l = 1; l < LVL; ++l) {
            const h8 vA = __builtin_nontemporal_load(reinterpret_cast<const h8*>(
                wl + ((size_t)((l << 10) + idxA[l]) << 10)));
            const h8 vB = __builtin_nontemporal_load(reinterpret_cast<const h8*>(
                wl + ((size_t)((l << 10) + idxB[l]) << 10)));
            accA += vA;
            accB += vB;
        }

        const f32x8 fA = __builtin_convertvector(accA, f32x8);
        const f32x8 fB = __builtin_convertvector(accB, f32x8);
        const f32x4 fA_lo = __builtin_shufflevector(fA, fA, 0, 1, 2, 3);
        const f32x4 fA_hi = __builtin_shufflevector(fA, fA, 4, 5, 6, 7);
        const f32x4 fB_lo = __builtin_shufflevector(fB, fB, 0, 1, 2, 3);
        const f32x4 fB_hi = __builtin_shufflevector(fB, fB, 4, 5, 6, 7);

        float* oA = out + (size_t)(ns0 + rowA) * DD + (size_t)chunk * DCH
                        + (size_t)lane * 8;
        float* oB = out + (size_t)(ns0 + rowB) * DD + (size_t)chunk * DCH
                        + (size_t)lane * 8;
        __builtin_nontemporal_store(fA_lo, reinterpret_cast<f32x4*>(oA));
        __builtin_nontemporal_store(fA_hi, reinterpret_cast<f32x4*>(oA) + 1);
        __builtin_nontemporal_store(fB_lo, reinterpret_cast<f32x4*>(oB));
        __builtin_nontemporal_store(fB_hi, reinterpret_cast<f32x4*>(oB) + 1);
    }
}

extern "C" void kernel_launch(void* const* d_in, const int* in_sizes, int n_in,
                              void* d_out, int out_size, void* d_ws, size_t ws_size,
                              hipStream_t stream) {
    const int*   x = (const int*)d_in[0];
    const float* w = (const float*)d_in[1];
    float*     out = (float*)d_out;
    _Float16*   wh = (_Float16*)d_ws;   // 16 MiB fp16 weight copy

    // 8 Mi elements / (256 thr * 16) = 2048 blocks
    convert_w_kernel<<<dim3((LVL * KK * DD) / (THREADS * 16)), dim3(THREADS), 0, stream>>>(w, wh);
    // 256 row-groups * 8 chunks = 2048 blocks
    multi_embedding_kernel<<<dim3((NS / 64) * NCH), dim3(THREADS), 0, stream>>>(x, wh, out);
}